// Round 9
// baseline (521.486 us; speedup 1.0000x reference)
//
#include <hip/hip_runtime.h>
#include <hip/hip_fp16.h>

#define NEG_SLOPE 0.2f
#define BK_LOG 9
#define BK_NODES (1 << BK_LOG)       // 512 nodes per bucket; bucket id < 256
#define TILE_EPT 24
#define TILE_E (256 * TILE_EPT)      // 6144 edges per partition tile

typedef __attribute__((ext_vector_type(8))) short bf8_t;   // 8 bf16 (4 VGPRs)
typedef __attribute__((ext_vector_type(4))) float f32x4;

// fp32 -> bf16 (RNE); inputs finite
__device__ __forceinline__ unsigned short f2bf(float f) {
    unsigned u = __float_as_uint(f);
    u += 0x7fffu + ((u >> 16) & 1u);
    return (unsigned short)(u >> 16);
}
__device__ __forceinline__ float bf2f(unsigned short h) {
    return __uint_as_float(((unsigned)h) << 16);
}

__device__ __forceinline__ int scan256_excl(int v, int* tmp) {
    int t = threadIdx.x;
    tmp[t] = v;
    __syncthreads();
    for (int d = 1; d < 256; d <<= 1) {
        int x = (t >= d) ? tmp[t - d] : 0;
        __syncthreads();
        tmp[t] += x;
        __syncthreads();
    }
    int r = tmp[t] - v;
    __syncthreads();
    return r;
}

// ---------------- edge partition (counting sort by dst-bucket) ----------------
// Pair record: (src << BK_LOG) | (dst & (BK_NODES-1)) -> 26 bits.
// Final edge record cw[]: (src << 15) | fp16(w)&0x7fff  (w>0 so sign bit free).

__global__ __launch_bounds__(256) void k_bzero(int* __restrict__ bcnt) {
    bcnt[threadIdx.x] = 0;
}

__global__ __launch_bounds__(256) void k_bcount(const int* __restrict__ edst,
                                                int* __restrict__ bcnt, int E) {
    __shared__ int th[256];
    int t = threadIdx.x;
    th[t] = 0;
    __syncthreads();
    int base = blockIdx.x * TILE_E;
#pragma unroll
    for (int k = 0; k < TILE_EPT; ++k) {
        int e = base + t + k * 256;
        if (e < E) atomicAdd(&th[edst[e] >> BK_LOG], 1);
    }
    __syncthreads();
    if (th[t]) atomicAdd(&bcnt[t], th[t]);
}

__global__ __launch_bounds__(256) void k_bscan(const int* __restrict__ bcnt,
                                               int* __restrict__ bbase,
                                               int* __restrict__ bcur,
                                               int* __restrict__ off, int N, int E) {
    __shared__ int tmp[256];
    int t = threadIdx.x;
    int ex = scan256_excl(bcnt[t], tmp);
    bbase[t] = ex;
    bcur[t]  = ex;
    if (t == 0) { bbase[256] = E; off[N] = E; }
}

__global__ __launch_bounds__(256) void k_bplace(const int* __restrict__ esrc,
                                                const int* __restrict__ edst,
                                                int* __restrict__ bcur,
                                                unsigned* __restrict__ pairs, int E) {
    __shared__ unsigned sp[TILE_E];
    __shared__ unsigned char sb[TILE_E];
    __shared__ int th[256], tx[256], rb[256], tmp[256];
    int t = threadIdx.x;
    th[t] = 0;
    __syncthreads();
    int base = blockIdx.x * TILE_E;
    int tot  = min(TILE_E, E - base);
#pragma unroll
    for (int k = 0; k < TILE_EPT; ++k) {
        int e = base + t + k * 256;
        if (e < E) atomicAdd(&th[edst[e] >> BK_LOG], 1);
    }
    __syncthreads();
    int cnt = th[t];
    tx[t] = scan256_excl(cnt, tmp);
    rb[t] = atomicAdd(&bcur[t], cnt);
    th[t] = 0;
    __syncthreads();
#pragma unroll
    for (int k = 0; k < TILE_EPT; ++k) {
        int e = base + t + k * 256;
        if (e < E) {
            int s = esrc[e], d = edst[e];
            int b = d >> BK_LOG;
            int r = atomicAdd(&th[b], 1);
            int pos = tx[b] + r;
            sp[pos] = ((unsigned)s << BK_LOG) | (unsigned)(d & (BK_NODES - 1));
            sb[pos] = (unsigned char)b;
        }
    }
    __syncthreads();
    for (int i = t; i < tot; i += 256) {
        int b = sb[i];
        pairs[rb[b] + (i - tx[b])] = sp[i];
    }
}

__global__ __launch_bounds__(256) void k_csr(const int* __restrict__ bbase,
                                             const unsigned* __restrict__ pairs,
                                             int* __restrict__ off,
                                             unsigned* __restrict__ cw, int N) {
    __shared__ int lh[BK_NODES], lx[BK_NODES];
    int b = blockIdx.x, t = threadIdx.x;
    int lo = bbase[b], hi = bbase[b + 1];
    int node0 = b << BK_LOG;
    lh[t] = 0; lh[t + 256] = 0;
    __syncthreads();
    for (int j = lo + t; j < hi; j += 256)
        atomicAdd(&lh[pairs[j] & (BK_NODES - 1)], 1);
    __syncthreads();
    lx[t] = lh[t]; lx[t + 256] = lh[t + 256];
    __syncthreads();
    for (int d = 1; d < BK_NODES; d <<= 1) {
        int i1 = t + 256;
        int x0 = (t  >= d) ? lx[t  - d] : 0;
        int x1 = (i1 >= d) ? lx[i1 - d] : 0;
        __syncthreads();
        lx[t] += x0; lx[i1] += x1;
        __syncthreads();
    }
    lx[t] -= lh[t]; lx[t + 256] -= lh[t + 256];
    if (node0 + t       < N) off[node0 + t]       = lo + lx[t];
    if (node0 + t + 256 < N) off[node0 + t + 256] = lo + lx[t + 256];
    lh[t] = 0; lh[t + 256] = 0;
    __syncthreads();
    for (int j = lo + t; j < hi; j += 256) {
        unsigned p  = pairs[j];
        int li = (int)(p & (BK_NODES - 1));
        int r  = atomicAdd(&lh[li], 1);
        cw[lo + lx[li] + r] = (p >> BK_LOG) << 15;   // src in bits [31:15]
    }
}

// ---------------- MFMA GEMM (split-bf16, fp32-class accuracy) ----------------
__global__ __launch_bounds__(256) void k_wsplit(const float* __restrict__ W,
                                                unsigned short* __restrict__ wh,
                                                unsigned short* __restrict__ wl,
                                                int K) {
    int idx = blockIdx.x * 256 + threadIdx.x;
    int KT = K >> 5;
    if (idx >= KT * 128) return;
    int lane = idx & 63;
    int nt = (idx >> 6) & 1;
    int kt = idx >> 7;
    int q = lane >> 4, c = lane & 15;
#pragma unroll
    for (int j = 0; j < 8; ++j) {
        int k = kt * 32 + q * 8 + j;
        int n = nt * 16 + c;
        float w = W[k * 32 + n];
        unsigned short hi = f2bf(w);
        wh[idx * 8 + j] = hi;
        wl[idx * 8 + j] = f2bf(w - bf2f(hi));
    }
}

template <int FIN, bool ATT>
__global__ __launch_bounds__(256) void gemm_mfma(
    const float* __restrict__ x,
    const unsigned short* __restrict__ wh, const unsigned short* __restrict__ wl,
    const float* __restrict__ a_s, const float* __restrict__ a_d,
    const float* __restrict__ bias,
    float* __restrict__ h, __half* __restrict__ h16a, __half* __restrict__ h16b,
    float* __restrict__ alpha_s, float* __restrict__ alpha_d, int N)
{
    constexpr int KT = FIN / 32;
    int lane = threadIdx.x & 63;
    int mt   = blockIdx.x * 4 + (threadIdx.x >> 6);
    int m0   = mt * 16;
    if (m0 >= N) return;
    int q = lane >> 4, c = lane & 15;

    bf8_t Bh[KT][2], Bl[KT][2];
#pragma unroll
    for (int kt = 0; kt < KT; ++kt)
#pragma unroll
        for (int nt = 0; nt < 2; ++nt) {
            Bh[kt][nt] = *(const bf8_t*)(wh + ((size_t)(kt * 2 + nt) * 64 + lane) * 8);
            Bl[kt][nt] = *(const bf8_t*)(wl + ((size_t)(kt * 2 + nt) * 64 + lane) * 8);
        }

    int rowa = m0 + c;
    if (rowa >= N) rowa = N - 1;
    const float* xr = x + (size_t)rowa * FIN;
    bf8_t Ah[KT], Al[KT];
#pragma unroll
    for (int kt = 0; kt < KT; ++kt) {
        f32x4 v0 = *(const f32x4*)(xr + kt * 32 + q * 8);
        f32x4 v1 = *(const f32x4*)(xr + kt * 32 + q * 8 + 4);
#pragma unroll
        for (int j = 0; j < 8; ++j) {
            float f = (j < 4) ? v0[j] : v1[j - 4];
            unsigned short hi = f2bf(f);
            Ah[kt][j] = (short)hi;
            Al[kt][j] = (short)f2bf(f - bf2f(hi));
        }
    }

    f32x4 acc0 = {0.f, 0.f, 0.f, 0.f}, acc1 = {0.f, 0.f, 0.f, 0.f};
#pragma unroll
    for (int kt = 0; kt < KT; ++kt) {
        acc0 = __builtin_amdgcn_mfma_f32_16x16x32_bf16(Ah[kt], Bh[kt][0], acc0, 0, 0, 0);
        acc1 = __builtin_amdgcn_mfma_f32_16x16x32_bf16(Ah[kt], Bh[kt][1], acc1, 0, 0, 0);
        acc0 = __builtin_amdgcn_mfma_f32_16x16x32_bf16(Al[kt], Bh[kt][0], acc0, 0, 0, 0);
        acc1 = __builtin_amdgcn_mfma_f32_16x16x32_bf16(Al[kt], Bh[kt][1], acc1, 0, 0, 0);
        acc0 = __builtin_amdgcn_mfma_f32_16x16x32_bf16(Ah[kt], Bl[kt][0], acc0, 0, 0, 0);
        acc1 = __builtin_amdgcn_mfma_f32_16x16x32_bf16(Ah[kt], Bl[kt][1], acc1, 0, 0, 0);
    }

#pragma unroll
    for (int reg = 0; reg < 4; ++reg) {
        int r = m0 + q * 4 + reg;
        if (r < N) {
            float v0s = acc0[reg], v1s = acc1[reg];
            if (!ATT) { v0s += bias[c]; v1s += bias[c + 16]; }
            h[(size_t)r * 32 + c]      = v0s;
            h[(size_t)r * 32 + 16 + c] = v1s;
            if (ATT) {   // half-feature fp16 copies (3.2 MB each -> XCD-L2-resident)
                h16a[(size_t)r * 16 + c] = __float2half(v0s);
                h16b[(size_t)r * 16 + c] = __float2half(v1s);
            }
        }
    }
    if (ATT) {
        float as0 = a_s[c], as1 = a_s[c + 16];
        float ad0 = a_d[c], ad1 = a_d[c + 16];
#pragma unroll
        for (int reg = 0; reg < 4; ++reg) {
            float ps = acc0[reg] * as0 + acc1[reg] * as1;
            float pd = acc0[reg] * ad0 + acc1[reg] * ad1;
#pragma unroll
            for (int msk = 8; msk >= 1; msk >>= 1) {
                ps += __shfl_xor(ps, msk);
                pd += __shfl_xor(pd, msk);
            }
            int r = m0 + q * 4 + reg;
            if (c == 0 && r < N) {
                alpha_s[r] = ps;
                alpha_d[r] = pd;
            }
        }
    }
}

// ---------------- aggregation ----------------

// Per-edge weights packed into cw's low 15 bits (fp16, sign dropped: w>0);
// also den/self-weight. src (bits 31:15) preserved -> layer 2 re-decodes.
__global__ __launch_bounds__(256) void k_edgew(
    unsigned* __restrict__ cw, const int* __restrict__ off,
    const float* __restrict__ alpha_s, const float* __restrict__ alpha_d,
    float* __restrict__ den, float* __restrict__ wsf, int N)
{
    int t = blockIdx.x * 256 + threadIdx.x;
    int i = t >> 5, k = t & 31;
    if (i >= N) return;
    int s0 = off[i], s1 = off[i + 1];
    float ad = alpha_d[i];
    float dp = 0.0f;
    for (int j = s0 + k; j < s1; j += 32) {
        unsigned p = cw[j];
        float tv = alpha_s[p >> 15] + ad;
        float lw = __expf(fmaxf(tv, 0.f) + NEG_SLOPE * fminf(tv, 0.f));
        cw[j] = (p & 0xFFFF8000u) |
                (unsigned)(__half_as_ushort(__float2half(lw)) & 0x7fff);
        dp += lw;
    }
#pragma unroll
    for (int m = 16; m >= 1; m >>= 1) dp += __shfl_xor(dp, m, 32);
    if (k == 0) {
        float tv = alpha_s[i] + ad;
        float ws_ = __expf(fmaxf(tv, 0.f) + NEG_SLOPE * fminf(tv, 0.f));
        den[i] = dp + ws_;
        wsf[i] = ws_;
    }
}

// One pass over HALF the features (16 cols): gather array is 3.2 MB ->
// L2-resident per XCD. 32 lanes/node = 2 halves x 16 features; the two
// halves process alternate edges, merged by shfl_xor(16) at the end.
// cw stream loaded non-temporally so it can't evict the gather array.
__global__ __launch_bounds__(256) void fused_agg(
    const unsigned* __restrict__ cw, const int* __restrict__ off,
    const float* __restrict__ den, const float* __restrict__ wsf,
    const float* __restrict__ h, const __half* __restrict__ h16p,
    const float* __restrict__ bias, float* __restrict__ out, int N, int col0)
{
    int t = blockIdx.x * 256 + threadIdx.x;
    int i = t >> 5;
    int lane = t & 31;
    int half = lane >> 4, k = lane & 15;
    if (i >= N) return;
    int s0 = off[i], s1 = off[i + 1];
    float acc = 0.0f;
    int j = s0;
    for (; j + 8 <= s1; j += 8) {
        unsigned p0 = __builtin_nontemporal_load(cw + j + half);
        unsigned p1 = __builtin_nontemporal_load(cw + j + 2 + half);
        unsigned p2 = __builtin_nontemporal_load(cw + j + 4 + half);
        unsigned p3 = __builtin_nontemporal_load(cw + j + 6 + half);
        float w0 = __half2float(__ushort_as_half((unsigned short)(p0 & 0x7fff)));
        float w1 = __half2float(__ushort_as_half((unsigned short)(p1 & 0x7fff)));
        float w2 = __half2float(__ushort_as_half((unsigned short)(p2 & 0x7fff)));
        float w3 = __half2float(__ushort_as_half((unsigned short)(p3 & 0x7fff)));
        acc += w0 * __half2float(h16p[(size_t)(p0 >> 15) * 16 + k]);
        acc += w1 * __half2float(h16p[(size_t)(p1 >> 15) * 16 + k]);
        acc += w2 * __half2float(h16p[(size_t)(p2 >> 15) * 16 + k]);
        acc += w3 * __half2float(h16p[(size_t)(p3 >> 15) * 16 + k]);
    }
    for (int idx = j + half; idx < s1; idx += 2) {
        unsigned p = __builtin_nontemporal_load(cw + idx);
        float w = __half2float(__ushort_as_half((unsigned short)(p & 0x7fff)));
        acc += w * __half2float(h16p[(size_t)(p >> 15) * 16 + k]);
    }
    acc += __shfl_xor(acc, 16, 32);   // merge the two edge-parity halves
    if (half == 0) {
        float v = (acc + wsf[i] * h[(size_t)i * 32 + col0 + k]) / den[i]
                  + bias[col0 + k];
        out[(size_t)i * 32 + col0 + k] = fmaxf(v, 0.0f);
    }
}

extern "C" void kernel_launch(void* const* d_in, const int* in_sizes, int n_in,
                              void* d_out, int out_size, void* d_ws, size_t ws_size,
                              hipStream_t stream)
{
    const float* x   = (const float*)d_in[0];
    const int*   ei  = (const int*)d_in[1];
    const float* W1  = (const float*)d_in[2];
    const float* a1s = (const float*)d_in[3];
    const float* a1d = (const float*)d_in[4];
    const float* b1  = (const float*)d_in[5];
    const float* W2  = (const float*)d_in[6];
    const float* a2s = (const float*)d_in[7];
    const float* a2d = (const float*)d_in[8];
    const float* b2  = (const float*)d_in[9];
    const float* Wf  = (const float*)d_in[10];
    const float* bf  = (const float*)d_in[11];

    const int N = in_sizes[0] / 128;
    const int E = in_sizes[1] / 2;
    const int* esrc = ei;
    const int* edst = ei + E;
    const int B1 = (N + BK_NODES - 1) >> BK_LOG;

    // Workspace (4B units): h1 32N | h2 32N | alpha_s N | alpha_d N | den N |
    //   wsf N | off N+1 | cw E | h16a 8N | h16b 8N | bcnt | bbase | bcur | wfrags
    float* ws = (float*)d_ws;
    float*    h1      = ws;
    float*    h2      = h1 + (size_t)N * 32;
    float*    alpha_s = h2 + (size_t)N * 32;
    float*    alpha_d = alpha_s + N;
    float*    den     = alpha_d + N;
    float*    wsf     = den + N;
    int*      off     = (int*)(wsf + N);
    unsigned* cw      = (unsigned*)(off + (N + 1));
    __half*   h16a    = (__half*)(cw + E);
    __half*   h16b    = h16a + (size_t)N * 16;
    int*      bcnt    = (int*)(h16b + (size_t)N * 16);
    int*      bbase   = bcnt + 256;
    int*      bcur    = bbase + 257;
    unsigned short* wfb =
        (unsigned short*)(((uintptr_t)(bcur + 256) + 15) & ~(uintptr_t)15);
    unsigned short* wh1 = wfb;
    unsigned short* wl1 = wh1 + 4096;
    unsigned short* wh2 = wl1 + 4096;
    unsigned short* wl2 = wh2 + 1024;
    unsigned short* whf = wl2 + 1024;
    unsigned short* wlf = whf + 1024;
    // pairs (E uints) aliases h1 (build completes before h is live)
    unsigned* pairs = ((size_t)E <= (size_t)32 * N)
                          ? (unsigned*)h1
                          : (unsigned*)(wlf + 1024);

    const int nb_node = (N * 32 + 255) / 256;
    const int nb_tile = (E + TILE_E - 1) / TILE_E;
    const int nb_gemm = ((N + 15) / 16 + 3) / 4;

    k_wsplit<<<2, 256, 0, stream>>>(W1, wh1, wl1, 128);
    k_wsplit<<<1, 256, 0, stream>>>(W2, wh2, wl2, 32);
    k_wsplit<<<1, 256, 0, stream>>>(Wf, whf, wlf, 32);

    k_bzero  <<<1, 256, 0, stream>>>(bcnt);
    k_bcount <<<nb_tile, 256, 0, stream>>>(edst, bcnt, E);
    k_bscan  <<<1, 256, 0, stream>>>(bcnt, bbase, bcur, off, N, E);
    k_bplace <<<nb_tile, 256, 0, stream>>>(esrc, edst, bcur, pairs, E);
    k_csr    <<<B1, 256, 0, stream>>>(bbase, pairs, off, cw, N);

    // ---- layer 1 ----
    gemm_mfma<128, true><<<nb_gemm, 256, 0, stream>>>(
        x, wh1, wl1, a1s, a1d, nullptr, h1, h16a, h16b, alpha_s, alpha_d, N);
    k_edgew<<<nb_node, 256, 0, stream>>>(cw, off, alpha_s, alpha_d, den, wsf, N);
    fused_agg<<<nb_node, 256, 0, stream>>>(cw, off, den, wsf, h1, h16a, b1, h2, N, 0);
    fused_agg<<<nb_node, 256, 0, stream>>>(cw, off, den, wsf, h1, h16b, b1, h2, N, 16);

    // ---- layer 2 ----
    gemm_mfma<32, true><<<nb_gemm, 256, 0, stream>>>(
        h2, wh2, wl2, a2s, a2d, nullptr, h1, h16a, h16b, alpha_s, alpha_d, N);
    k_edgew<<<nb_node, 256, 0, stream>>>(cw, off, alpha_s, alpha_d, den, wsf, N);
    fused_agg<<<nb_node, 256, 0, stream>>>(cw, off, den, wsf, h1, h16a, b2, h2, N, 0);
    fused_agg<<<nb_node, 256, 0, stream>>>(cw, off, den, wsf, h1, h16b, b2, h2, N, 16);

    // ---- final linear ----
    gemm_mfma<32, false><<<nb_gemm, 256, 0, stream>>>(
        h2, whf, wlf, nullptr, nullptr, bf, (float*)d_out, nullptr, nullptr,
        nullptr, nullptr, N);
}

// Round 10
// 405.240 us; speedup vs baseline: 1.2869x; 1.2869x over previous
//
#include <hip/hip_runtime.h>
#include <hip/hip_fp16.h>

#define NEG_SLOPE 0.2f
#define BK_LOG 9
#define BK_NODES (1 << BK_LOG)       // 512 nodes per bucket; bucket id < 256
#define TILE_EPT 24
#define TILE_E (256 * TILE_EPT)      // 6144 edges per partition tile

typedef __attribute__((ext_vector_type(8))) short bf8_t;   // 8 bf16 (4 VGPRs)
typedef __attribute__((ext_vector_type(4))) float f32x4;

// fp32 -> bf16 (RNE); inputs finite
__device__ __forceinline__ unsigned short f2bf(float f) {
    unsigned u = __float_as_uint(f);
    u += 0x7fffu + ((u >> 16) & 1u);
    return (unsigned short)(u >> 16);
}
__device__ __forceinline__ float bf2f(unsigned short h) {
    return __uint_as_float(((unsigned)h) << 16);
}

__device__ __forceinline__ int scan256_excl(int v, int* tmp) {
    int t = threadIdx.x;
    tmp[t] = v;
    __syncthreads();
    for (int d = 1; d < 256; d <<= 1) {
        int x = (t >= d) ? tmp[t - d] : 0;
        __syncthreads();
        tmp[t] += x;
        __syncthreads();
    }
    int r = tmp[t] - v;
    __syncthreads();
    return r;
}

// ---------------- edge partition (counting sort by dst-bucket) ----------------
// Pair record: (src << BK_LOG) | (dst & (BK_NODES-1)) -> 26 bits.

__global__ __launch_bounds__(256) void k_bzero(int* __restrict__ bcnt) {
    bcnt[threadIdx.x] = 0;
}

__global__ __launch_bounds__(256) void k_bcount(const int* __restrict__ edst,
                                                int* __restrict__ bcnt, int E) {
    __shared__ int th[256];
    int t = threadIdx.x;
    th[t] = 0;
    __syncthreads();
    int base = blockIdx.x * TILE_E;
#pragma unroll
    for (int k = 0; k < TILE_EPT; ++k) {
        int e = base + t + k * 256;
        if (e < E) atomicAdd(&th[edst[e] >> BK_LOG], 1);
    }
    __syncthreads();
    if (th[t]) atomicAdd(&bcnt[t], th[t]);
}

__global__ __launch_bounds__(256) void k_bscan(const int* __restrict__ bcnt,
                                               int* __restrict__ bbase,
                                               int* __restrict__ bcur,
                                               int* __restrict__ off, int N, int E) {
    __shared__ int tmp[256];
    int t = threadIdx.x;
    int ex = scan256_excl(bcnt[t], tmp);
    bbase[t] = ex;
    bcur[t]  = ex;
    if (t == 0) { bbase[256] = E; off[N] = E; }
}

__global__ __launch_bounds__(256) void k_bplace(const int* __restrict__ esrc,
                                                const int* __restrict__ edst,
                                                int* __restrict__ bcur,
                                                unsigned* __restrict__ pairs, int E) {
    __shared__ unsigned sp[TILE_E];
    __shared__ unsigned char sb[TILE_E];
    __shared__ int th[256], tx[256], rb[256], tmp[256];
    int t = threadIdx.x;
    th[t] = 0;
    __syncthreads();
    int base = blockIdx.x * TILE_E;
    int tot  = min(TILE_E, E - base);
#pragma unroll
    for (int k = 0; k < TILE_EPT; ++k) {
        int e = base + t + k * 256;
        if (e < E) atomicAdd(&th[edst[e] >> BK_LOG], 1);
    }
    __syncthreads();
    int cnt = th[t];
    tx[t] = scan256_excl(cnt, tmp);
    rb[t] = atomicAdd(&bcur[t], cnt);
    th[t] = 0;
    __syncthreads();
#pragma unroll
    for (int k = 0; k < TILE_EPT; ++k) {
        int e = base + t + k * 256;
        if (e < E) {
            int s = esrc[e], d = edst[e];
            int b = d >> BK_LOG;
            int r = atomicAdd(&th[b], 1);
            int pos = tx[b] + r;
            sp[pos] = ((unsigned)s << BK_LOG) | (unsigned)(d & (BK_NODES - 1));
            sb[pos] = (unsigned char)b;
        }
    }
    __syncthreads();
    for (int i = t; i < tot; i += 256) {
        int b = sb[i];
        pairs[rb[b] + (i - tx[b])] = sp[i];
    }
}

__global__ __launch_bounds__(256) void k_csr(const int* __restrict__ bbase,
                                             const unsigned* __restrict__ pairs,
                                             int* __restrict__ off,
                                             int* __restrict__ csr, int N) {
    __shared__ int lh[BK_NODES], lx[BK_NODES];
    int b = blockIdx.x, t = threadIdx.x;
    int lo = bbase[b], hi = bbase[b + 1];
    int node0 = b << BK_LOG;
    lh[t] = 0; lh[t + 256] = 0;
    __syncthreads();
    for (int j = lo + t; j < hi; j += 256)
        atomicAdd(&lh[pairs[j] & (BK_NODES - 1)], 1);
    __syncthreads();
    lx[t] = lh[t]; lx[t + 256] = lh[t + 256];
    __syncthreads();
    for (int d = 1; d < BK_NODES; d <<= 1) {
        int i1 = t + 256;
        int x0 = (t  >= d) ? lx[t  - d] : 0;
        int x1 = (i1 >= d) ? lx[i1 - d] : 0;
        __syncthreads();
        lx[t] += x0; lx[i1] += x1;
        __syncthreads();
    }
    lx[t] -= lh[t]; lx[t + 256] -= lh[t + 256];
    if (node0 + t       < N) off[node0 + t]       = lo + lx[t];
    if (node0 + t + 256 < N) off[node0 + t + 256] = lo + lx[t + 256];
    lh[t] = 0; lh[t + 256] = 0;
    __syncthreads();
    for (int j = lo + t; j < hi; j += 256) {
        unsigned p  = pairs[j];
        int li = (int)(p & (BK_NODES - 1));
        int r  = atomicAdd(&lh[li], 1);
        csr[lo + lx[li] + r] = (int)(p >> BK_LOG);
    }
}

// ---------------- MFMA GEMM (split-bf16, fp32-class accuracy) ----------------
// One kernel splits all three weight matrices (W1:K=128 blocks 0-1, W2: block 2,
// Wf: block 3) to cut launch count.
__global__ __launch_bounds__(256) void k_wsplit3(
    const float* __restrict__ W1, unsigned short* __restrict__ wh1, unsigned short* __restrict__ wl1,
    const float* __restrict__ W2, unsigned short* __restrict__ wh2, unsigned short* __restrict__ wl2,
    const float* __restrict__ Wf, unsigned short* __restrict__ whf, unsigned short* __restrict__ wlf)
{
    const float* W; unsigned short *wh, *wl; int idx;
    if (blockIdx.x < 2) { W = W1; wh = wh1; wl = wl1; idx = blockIdx.x * 256 + threadIdx.x; }
    else if (blockIdx.x == 2) { W = W2; wh = wh2; wl = wl2; idx = threadIdx.x; }
    else { W = Wf; wh = whf; wl = wlf; idx = threadIdx.x; }
    if (blockIdx.x >= 2 && idx >= 128) return;   // K=32 -> 128 fragments
    int lane = idx & 63;
    int nt = (idx >> 6) & 1;
    int kt = idx >> 7;
    int q = lane >> 4, c = lane & 15;
#pragma unroll
    for (int j = 0; j < 8; ++j) {
        int k = kt * 32 + q * 8 + j;
        int n = nt * 16 + c;
        float w = W[k * 32 + n];
        unsigned short hi = f2bf(w);
        wh[idx * 8 + j] = hi;
        wl[idx * 8 + j] = f2bf(w - bf2f(hi));
    }
}

template <int FIN, bool ATT>
__global__ __launch_bounds__(256) void gemm_mfma(
    const float* __restrict__ x,
    const unsigned short* __restrict__ wh, const unsigned short* __restrict__ wl,
    const float* __restrict__ a_s, const float* __restrict__ a_d,
    const float* __restrict__ bias,
    float* __restrict__ h, __half* __restrict__ h16,
    float* __restrict__ alpha_s, float* __restrict__ alpha_d, int N)
{
    constexpr int KT = FIN / 32;
    int lane = threadIdx.x & 63;
    int mt   = blockIdx.x * 4 + (threadIdx.x >> 6);
    int m0   = mt * 16;
    if (m0 >= N) return;
    int q = lane >> 4, c = lane & 15;

    bf8_t Bh[KT][2], Bl[KT][2];
#pragma unroll
    for (int kt = 0; kt < KT; ++kt)
#pragma unroll
        for (int nt = 0; nt < 2; ++nt) {
            Bh[kt][nt] = *(const bf8_t*)(wh + ((size_t)(kt * 2 + nt) * 64 + lane) * 8);
            Bl[kt][nt] = *(const bf8_t*)(wl + ((size_t)(kt * 2 + nt) * 64 + lane) * 8);
        }

    int rowa = m0 + c;
    if (rowa >= N) rowa = N - 1;
    const float* xr = x + (size_t)rowa * FIN;
    bf8_t Ah[KT], Al[KT];
#pragma unroll
    for (int kt = 0; kt < KT; ++kt) {
        f32x4 v0 = *(const f32x4*)(xr + kt * 32 + q * 8);
        f32x4 v1 = *(const f32x4*)(xr + kt * 32 + q * 8 + 4);
#pragma unroll
        for (int j = 0; j < 8; ++j) {
            float f = (j < 4) ? v0[j] : v1[j - 4];
            unsigned short hi = f2bf(f);
            Ah[kt][j] = (short)hi;
            Al[kt][j] = (short)f2bf(f - bf2f(hi));
        }
    }

    f32x4 acc0 = {0.f, 0.f, 0.f, 0.f}, acc1 = {0.f, 0.f, 0.f, 0.f};
#pragma unroll
    for (int kt = 0; kt < KT; ++kt) {
        acc0 = __builtin_amdgcn_mfma_f32_16x16x32_bf16(Ah[kt], Bh[kt][0], acc0, 0, 0, 0);
        acc1 = __builtin_amdgcn_mfma_f32_16x16x32_bf16(Ah[kt], Bh[kt][1], acc1, 0, 0, 0);
        acc0 = __builtin_amdgcn_mfma_f32_16x16x32_bf16(Al[kt], Bh[kt][0], acc0, 0, 0, 0);
        acc1 = __builtin_amdgcn_mfma_f32_16x16x32_bf16(Al[kt], Bh[kt][1], acc1, 0, 0, 0);
        acc0 = __builtin_amdgcn_mfma_f32_16x16x32_bf16(Ah[kt], Bl[kt][0], acc0, 0, 0, 0);
        acc1 = __builtin_amdgcn_mfma_f32_16x16x32_bf16(Ah[kt], Bl[kt][1], acc1, 0, 0, 0);
    }

#pragma unroll
    for (int reg = 0; reg < 4; ++reg) {
        int r = m0 + q * 4 + reg;
        if (r < N) {
            float v0s = acc0[reg], v1s = acc1[reg];
            if (!ATT) { v0s += bias[c]; v1s += bias[c + 16]; }
            h[(size_t)r * 32 + c]      = v0s;
            h[(size_t)r * 32 + 16 + c] = v1s;
            if (ATT) {   // fp16 copy for the gather phase
                h16[(size_t)r * 32 + c]      = __float2half(v0s);
                h16[(size_t)r * 32 + 16 + c] = __float2half(v1s);
            }
        }
    }
    if (ATT) {
        float as0 = a_s[c], as1 = a_s[c + 16];
        float ad0 = a_d[c], ad1 = a_d[c + 16];
#pragma unroll
        for (int reg = 0; reg < 4; ++reg) {
            float ps = acc0[reg] * as0 + acc1[reg] * as1;
            float pd = acc0[reg] * ad0 + acc1[reg] * ad1;
#pragma unroll
            for (int msk = 8; msk >= 1; msk >>= 1) {
                ps += __shfl_xor(ps, msk);
                pd += __shfl_xor(pd, msk);
            }
            int r = m0 + q * 4 + reg;
            if (c == 0 && r < N) {
                alpha_s[r] = ps;
                alpha_d[r] = pd;
            }
        }
    }
}

// ---------------- aggregation (single pass, fused weights) ----------------
// One 32-lane group per node, lane k = feature k. Per 32-edge chunk:
// lane j cooperatively computes edge j's softmax weight (one exp per edge
// TOTAL) into LDS (value path only); the gather loop takes addresses from
// affine global csr broadcasts (R6 lesson: never put cross-lane data on the
// address path) and weights from LDS.
__global__ __launch_bounds__(256) void fused_agg(
    const int* __restrict__ csr, const int* __restrict__ off,
    const float* __restrict__ alpha_s, const float* __restrict__ alpha_d,
    const float* __restrict__ h, const __half* __restrict__ h16,
    const float* __restrict__ bias, float* __restrict__ out, int N)
{
    __shared__ float wbuf[8][32];
    int t = blockIdx.x * 256 + threadIdx.x;
    int i = t >> 5, k = t & 31;
    int grp = threadIdx.x >> 5;
    if (i >= N) return;
    int s0 = off[i], s1 = off[i + 1];
    float ad  = alpha_d[i];
    float tvs = alpha_s[i] + ad;
    float wself = __expf(fmaxf(tvs, 0.f) + NEG_SLOPE * fminf(tvs, 0.f));
    float acc  = wself * h[(size_t)i * 32 + k];   // self term in fp32
    float denp = 0.0f;                             // per-lane partial
    for (int c0 = s0; c0 < s1; c0 += 32) {
        int n = s1 - c0; if (n > 32) n = 32;
        // cooperative weight computation: lane j -> edge c0+j
        int   cs = csr[c0 + (k < n ? k : n - 1)];        // coalesced
        float tv = alpha_s[cs] + ad;                     // 400 KB, L2-hit
        float lw = (k < n)
                       ? __expf(fmaxf(tv, 0.f) + NEG_SLOPE * fminf(tv, 0.f))
                       : 0.0f;
        wbuf[grp][k] = lw;       // same-wave write->read; compiler waits lgkmcnt
        denp += lw;
        int j = 0;
        for (; j + 8 <= n; j += 8) {
            int c0_ = csr[c0 + j],     c1_ = csr[c0 + j + 1];
            int c2_ = csr[c0 + j + 2], c3_ = csr[c0 + j + 3];
            int c4_ = csr[c0 + j + 4], c5_ = csr[c0 + j + 5];
            int c6_ = csr[c0 + j + 6], c7_ = csr[c0 + j + 7];
            float w0 = wbuf[grp][j],     w1 = wbuf[grp][j + 1];
            float w2 = wbuf[grp][j + 2], w3 = wbuf[grp][j + 3];
            float w4 = wbuf[grp][j + 4], w5 = wbuf[grp][j + 5];
            float w6 = wbuf[grp][j + 6], w7 = wbuf[grp][j + 7];
            acc += w0 * __half2float(h16[(size_t)c0_ * 32 + k]);
            acc += w1 * __half2float(h16[(size_t)c1_ * 32 + k]);
            acc += w2 * __half2float(h16[(size_t)c2_ * 32 + k]);
            acc += w3 * __half2float(h16[(size_t)c3_ * 32 + k]);
            acc += w4 * __half2float(h16[(size_t)c4_ * 32 + k]);
            acc += w5 * __half2float(h16[(size_t)c5_ * 32 + k]);
            acc += w6 * __half2float(h16[(size_t)c6_ * 32 + k]);
            acc += w7 * __half2float(h16[(size_t)c7_ * 32 + k]);
        }
        for (; j < n; ++j)
            acc += wbuf[grp][j] * __half2float(h16[(size_t)csr[c0 + j] * 32 + k]);
    }
#pragma unroll
    for (int m = 16; m >= 1; m >>= 1) denp += __shfl_xor(denp, m, 32);
    float v = acc / (denp + wself) + bias[k];
    out[(size_t)i * 32 + k] = fmaxf(v, 0.0f);
}

extern "C" void kernel_launch(void* const* d_in, const int* in_sizes, int n_in,
                              void* d_out, int out_size, void* d_ws, size_t ws_size,
                              hipStream_t stream)
{
    const float* x   = (const float*)d_in[0];
    const int*   ei  = (const int*)d_in[1];
    const float* W1  = (const float*)d_in[2];
    const float* a1s = (const float*)d_in[3];
    const float* a1d = (const float*)d_in[4];
    const float* b1  = (const float*)d_in[5];
    const float* W2  = (const float*)d_in[6];
    const float* a2s = (const float*)d_in[7];
    const float* a2d = (const float*)d_in[8];
    const float* b2  = (const float*)d_in[9];
    const float* Wf  = (const float*)d_in[10];
    const float* bf  = (const float*)d_in[11];

    const int N = in_sizes[0] / 128;
    const int E = in_sizes[1] / 2;
    const int* esrc = ei;
    const int* edst = ei + E;
    const int B1 = (N + BK_NODES - 1) >> BK_LOG;

    // Workspace (4B units): h1 32N | h2 32N | alpha_s N | alpha_d N |
    //   off N+1 | csr E | h16 16N | bcnt 256 | bbase 257 | bcur 256 | wfrags
    float* ws = (float*)d_ws;
    float*  h1      = ws;
    float*  h2      = h1 + (size_t)N * 32;
    float*  alpha_s = h2 + (size_t)N * 32;
    float*  alpha_d = alpha_s + N;
    int*    off     = (int*)(alpha_d + N);
    int*    csr     = off + (N + 1);
    __half* h16     = (__half*)(csr + E);
    int*    bcnt    = (int*)(h16 + (size_t)N * 32);
    int*    bbase   = bcnt + 256;
    int*    bcur    = bbase + 257;
    unsigned short* wfb =
        (unsigned short*)(((uintptr_t)(bcur + 256) + 15) & ~(uintptr_t)15);
    unsigned short* wh1 = wfb;
    unsigned short* wl1 = wh1 + 4096;
    unsigned short* wh2 = wl1 + 4096;
    unsigned short* wl2 = wh2 + 1024;
    unsigned short* whf = wl2 + 1024;
    unsigned short* wlf = whf + 1024;
    // pairs (E uints) aliases h1 (build completes before h is live)
    unsigned* pairs = ((size_t)E <= (size_t)32 * N)
                          ? (unsigned*)h1
                          : (unsigned*)(wlf + 1024);

    const int nb_node = (N * 32 + 255) / 256;
    const int nb_tile = (E + TILE_E - 1) / TILE_E;
    const int nb_gemm = ((N + 15) / 16 + 3) / 4;

    k_wsplit3<<<4, 256, 0, stream>>>(W1, wh1, wl1, W2, wh2, wl2, Wf, whf, wlf);

    k_bzero  <<<1, 256, 0, stream>>>(bcnt);
    k_bcount <<<nb_tile, 256, 0, stream>>>(edst, bcnt, E);
    k_bscan  <<<1, 256, 0, stream>>>(bcnt, bbase, bcur, off, N, E);
    k_bplace <<<nb_tile, 256, 0, stream>>>(esrc, edst, bcur, pairs, E);
    k_csr    <<<B1, 256, 0, stream>>>(bbase, pairs, off, csr, N);

    // ---- layer 1 ----
    gemm_mfma<128, true><<<nb_gemm, 256, 0, stream>>>(
        x, wh1, wl1, a1s, a1d, nullptr, h1, h16, alpha_s, alpha_d, N);
    fused_agg<<<nb_node, 256, 0, stream>>>(
        csr, off, alpha_s, alpha_d, h1, h16, b1, h2, N);

    // ---- layer 2 ----
    gemm_mfma<32, true><<<nb_gemm, 256, 0, stream>>>(
        h2, wh2, wl2, a2s, a2d, nullptr, h1, h16, alpha_s, alpha_d, N);
    fused_agg<<<nb_node, 256, 0, stream>>>(
        csr, off, alpha_s, alpha_d, h1, h16, b2, h2, N);

    // ---- final linear ----
    gemm_mfma<32, false><<<nb_gemm, 256, 0, stream>>>(
        h2, whf, wlf, nullptr, nullptr, bf, (float*)d_out, nullptr,
        nullptr, nullptr, N);
}